// Round 1
// baseline (528.711 us; speedup 1.0000x reference)
//
#include <hip/hip_runtime.h>
#include <math.h>

typedef float  f32x4 __attribute__((ext_vector_type(4)));
typedef short  s16x8 __attribute__((ext_vector_type(8)));
typedef unsigned short u16;

// ---------- bf16 helpers (bit-level, no hip_bf16 API dependence) ----------
static __device__ __forceinline__ u16 f32_to_bf16_rne(float f) {
    unsigned int u = __builtin_bit_cast(unsigned int, f);
    unsigned int r = u + 0x7fffu + ((u >> 16) & 1u);
    return (u16)(r >> 16);
}
static __device__ __forceinline__ float bf16_to_f32(u16 h) {
    return __builtin_bit_cast(float, (unsigned int)h << 16);
}

// Problem constants
// B=2, S=2048, E=2048, A=2048, H=16, HD=128; rows = B*S = 4096; qkv cols = 6144.

// ---------- 1) cast fp32 -> bf16 (4 elems/thread) ----------
__global__ void k_cast(const float* __restrict__ in, u16* __restrict__ out) {
    int i = (blockIdx.x * 256 + threadIdx.x) * 4;
    float4 v = *reinterpret_cast<const float4*>(in + i);
    ushort4 u;
    u.x = f32_to_bf16_rne(v.x); u.y = f32_to_bf16_rne(v.y);
    u.z = f32_to_bf16_rne(v.z); u.w = f32_to_bf16_rne(v.w);
    *reinterpret_cast<ushort4*>(out + i) = u;
}

// ---------- 2) transpose + cast: W (R x C fp32) -> Wt (C x R bf16) ----------
__global__ void k_transpose_cast(const float* __restrict__ in, u16* __restrict__ out,
                                 int R, int C) {
    __shared__ __align__(16) float tile[64 * 68];
    const int ct = blockIdx.x, rt = blockIdx.y;
    const int t = threadIdx.x;
    const int tr = t >> 4;          // 0..15
    const int tc4 = (t & 15) * 4;   // 0..60
#pragma unroll
    for (int rn = 0; rn < 4; ++rn) {
        int r = rn * 16 + tr;
        float4 v = *reinterpret_cast<const float4*>(in + (size_t)(rt * 64 + r) * C + ct * 64 + tc4);
        *reinterpret_cast<float4*>(&tile[r * 68 + tc4]) = v;
    }
    __syncthreads();
#pragma unroll
    for (int rn = 0; rn < 4; ++rn) {
        int oc = rn * 16 + tr;      // input col = output row (local)
        ushort4 u;
        u.x = f32_to_bf16_rne(tile[(tc4 + 0) * 68 + oc]);
        u.y = f32_to_bf16_rne(tile[(tc4 + 1) * 68 + oc]);
        u.z = f32_to_bf16_rne(tile[(tc4 + 2) * 68 + oc]);
        u.w = f32_to_bf16_rne(tile[(tc4 + 3) * 68 + oc]);
        *reinterpret_cast<ushort4*>(out + (size_t)(ct * 64 + oc) * R + rt * 64 + tc4) = u;
    }
}

// ---------- 3) GEMM: C[M,N] = A[M,K] * Bt[N,K]^T (bf16 in, fp32 acc) ----------
// 128x128 tile, BK=32, 4 waves, each wave 64x64 (4x4 of 16x16x32 mfma).
// LDS row stride 40 elems (80 B): frag reads 2-way bank aliased (free).
template<bool BF16OUT>
__global__ __launch_bounds__(256) void k_gemm_bt(const u16* __restrict__ Amat,
                                                 const u16* __restrict__ Bt,
                                                 void* __restrict__ Cout,
                                                 int M, int N, int K) {
    __shared__ __align__(16) u16 As[128 * 40];
    __shared__ __align__(16) u16 Bs[128 * 40];
    const int t = threadIdx.x;
    const int lane = t & 63, wave = t >> 6;
    const int m16 = lane & 15, qd = lane >> 4;
    const int wm = (wave >> 1) * 64, wn = (wave & 1) * 64;
    const size_t m0 = (size_t)blockIdx.y * 128, n0 = (size_t)blockIdx.x * 128;
    const int sr = t >> 2;          // 0..63
    const int sc = (t & 3) * 8;     // 0,8,16,24

    const u16* Aptr = Amat + (m0 + sr) * K + sc;
    const u16* Bptr = Bt   + (n0 + sr) * K + sc;

    f32x4 acc[4][4] = {};

    for (int k0 = 0; k0 < K; k0 += 32) {
        s16x8 a0 = *reinterpret_cast<const s16x8*>(Aptr + k0);
        s16x8 a1 = *reinterpret_cast<const s16x8*>(Aptr + (size_t)64 * K + k0);
        s16x8 b0 = *reinterpret_cast<const s16x8*>(Bptr + k0);
        s16x8 b1 = *reinterpret_cast<const s16x8*>(Bptr + (size_t)64 * K + k0);
        *reinterpret_cast<s16x8*>(&As[sr * 40 + sc])        = a0;
        *reinterpret_cast<s16x8*>(&As[(64 + sr) * 40 + sc]) = a1;
        *reinterpret_cast<s16x8*>(&Bs[sr * 40 + sc])        = b0;
        *reinterpret_cast<s16x8*>(&Bs[(64 + sr) * 40 + sc]) = b1;
        __syncthreads();
        s16x8 af[4], bf[4];
#pragma unroll
        for (int i = 0; i < 4; ++i)
            af[i] = *reinterpret_cast<const s16x8*>(&As[(wm + i * 16 + m16) * 40 + qd * 8]);
#pragma unroll
        for (int i = 0; i < 4; ++i)
            bf[i] = *reinterpret_cast<const s16x8*>(&Bs[(wn + i * 16 + m16) * 40 + qd * 8]);
#pragma unroll
        for (int i = 0; i < 4; ++i)
#pragma unroll
            for (int j = 0; j < 4; ++j)
                acc[i][j] = __builtin_amdgcn_mfma_f32_16x16x32_bf16(af[i], bf[j], acc[i][j], 0, 0, 0);
        __syncthreads();
    }
    // C/D layout: col = lane&15, row = (lane>>4)*4 + reg  [verified m89/m91]
#pragma unroll
    for (int i = 0; i < 4; ++i)
#pragma unroll
        for (int j = 0; j < 4; ++j)
#pragma unroll
            for (int r = 0; r < 4; ++r) {
                size_t row = m0 + wm + i * 16 + qd * 4 + r;
                size_t col = n0 + wn + j * 16 + m16;
                if (BF16OUT)
                    ((u16*)Cout)[row * N + col] = f32_to_bf16_rne(acc[i][j][r]);
                else
                    ((float*)Cout)[row * N + col] = acc[i][j][r];
            }
}

// ---------- 4) RoPE in-place on q,k halves of qkv (bf16) ----------
__global__ void k_rope(u16* __restrict__ qkv) {
    int idx = blockIdx.x * 256 + threadIdx.x;   // 4096 rows * 2048 pairs
    int row = idx >> 11;
    int p = idx & 2047;
    int s = row & 2047;
    int which = p >> 10;        // 0=q, 1=k
    int rem = p & 1023;
    int h = rem >> 6;
    int i = rem & 63;           // pair index
    size_t off = (size_t)row * 6144 + (size_t)which * 2048 + h * 128 + 2 * i;
    unsigned int v = *reinterpret_cast<unsigned int*>(qkv + off);
    float x1 = bf16_to_f32((u16)(v & 0xffffu));
    float x2 = bf16_to_f32((u16)(v >> 16));
    // inv_freq = 10000^(-2i/128) = exp(-ln(1e4)/64 * i)
    float inv = expf(-0.14391156831f * (float)i);
    float f = (float)s * inv;
    float cs = cosf(f), sn = sinf(f);
    float o1 = x1 * cs - x2 * sn;
    float o2 = x1 * sn + x2 * cs;
    unsigned int w = (unsigned int)f32_to_bf16_rne(o1) | ((unsigned int)f32_to_bf16_rne(o2) << 16);
    *reinterpret_cast<unsigned int*>(qkv + off) = w;
}

// ---------- 5) V -> V^T global: vt[bh][d][s] = qkv[b, s, 4096 + h*128 + d] ----------
__global__ void k_transpose_v(const u16* __restrict__ qkv, u16* __restrict__ vt) {
    __shared__ u16 tile[64 * 68];
    const int st = blockIdx.x;          // s tile (0..31)
    const int bhd = blockIdx.y;         // bh*2 + dt
    const int bh = bhd >> 1, dt = bhd & 1;
    const u16* src = qkv + (size_t)(bh >> 4) * 2048 * 6144 + 4096 + (size_t)(bh & 15) * 128 + dt * 64;
    const int t = threadIdx.x, tr = t >> 4, tc4 = (t & 15) * 4;
#pragma unroll
    for (int rn = 0; rn < 4; ++rn) {
        int s = rn * 16 + tr;
        *reinterpret_cast<ushort4*>(&tile[s * 68 + tc4]) =
            *reinterpret_cast<const ushort4*>(src + (size_t)(st * 64 + s) * 6144 + tc4);
    }
    __syncthreads();
    u16* dst = vt + ((size_t)bh * 128 + dt * 64) * 2048 + st * 64;
#pragma unroll
    for (int rn = 0; rn < 4; ++rn) {
        int d = rn * 16 + tr;
        ushort4 u;
        u.x = tile[(tc4 + 0) * 68 + d];
        u.y = tile[(tc4 + 1) * 68 + d];
        u.z = tile[(tc4 + 2) * 68 + d];
        u.w = tile[(tc4 + 3) * 68 + d];
        *reinterpret_cast<ushort4*>(dst + (size_t)d * 2048 + tc4) = u;
    }
}

// ---------- 6) flash attention: Q-tile 128, K-tile 128, online softmax ----------
// LDS row stride 152 elems (304 B = 76 dwords): all b128 phases <=2-way aliased.
// KP holds K-tile [s_k][d], then reused for P [s_q][s_k] after QK^T barrier.
__global__ __launch_bounds__(256, 2) void k_flash(const u16* __restrict__ qkv,
                                                  const u16* __restrict__ vt,
                                                  u16* __restrict__ out) {
    __shared__ __align__(16) u16 KP[128 * 152];
    __shared__ __align__(16) u16 VT[128 * 152];
    const int t = threadIdx.x, lane = t & 63, wave = t >> 6;
    const int m16 = lane & 15, qd = lane >> 4;
    const int bh = blockIdx.y, b = bh >> 4, h = bh & 15;
    const int q0 = blockIdx.x * 128;
    const int wq = wave * 32;
    const u16* Qg = qkv + (size_t)b * 2048 * 6144 + (size_t)h * 128;
    const u16* Kg = Qg + 2048;
    const u16* Vtg = vt + (size_t)bh * 128 * 2048;
    const float scale = 0.08838834764831845f;  // 1/sqrt(128)

    // Persistent Q fragments: A[m=lane&15][k=quad*8+j]  [m120-verified layout]
    s16x8 qf[2][4];
#pragma unroll
    for (int mi = 0; mi < 2; ++mi)
#pragma unroll
        for (int kc = 0; kc < 4; ++kc)
            qf[mi][kc] = *reinterpret_cast<const s16x8*>(
                Qg + (size_t)(q0 + wq + mi * 16 + m16) * 6144 + kc * 32 + qd * 8);

    f32x4 accO[2][8] = {};
    float mrow[2][4], lrow[2][4];
#pragma unroll
    for (int mi = 0; mi < 2; ++mi)
#pragma unroll
        for (int r = 0; r < 4; ++r) { mrow[mi][r] = -INFINITY; lrow[mi][r] = 0.f; }

    const int strow = t >> 4;        // 0..15
    const int stc = (t & 15) * 8;    // 0..120

    for (int kt = 0; kt < 16; ++kt) {
        const int s0 = kt * 128;
        __syncthreads();   // prev iter's PV reads done before overwrite
#pragma unroll
        for (int rd = 0; rd < 8; ++rd) {
            int row = rd * 16 + strow;
            *reinterpret_cast<s16x8*>(&KP[row * 152 + stc]) =
                *reinterpret_cast<const s16x8*>(Kg + (size_t)(s0 + row) * 6144 + stc);
            *reinterpret_cast<s16x8*>(&VT[row * 152 + stc]) =
                *reinterpret_cast<const s16x8*>(Vtg + (size_t)row * 2048 + s0 + stc);
        }
        __syncthreads();

        // QK^T: B-frag = K[s_k = nj*16+m16][d = kc*32+qd*8+j]
        f32x4 accS[2][8] = {};
#pragma unroll
        for (int kc = 0; kc < 4; ++kc)
#pragma unroll
            for (int nj = 0; nj < 8; ++nj) {
                s16x8 kf = *reinterpret_cast<const s16x8*>(&KP[(nj * 16 + m16) * 152 + kc * 32 + qd * 8]);
                accS[0][nj] = __builtin_amdgcn_mfma_f32_16x16x32_bf16(qf[0][kc], kf, accS[0][nj], 0, 0, 0);
                accS[1][nj] = __builtin_amdgcn_mfma_f32_16x16x32_bf16(qf[1][kc], kf, accS[1][nj], 0, 0, 0);
            }
        __syncthreads();   // everyone done reading K before P overwrites KP

        // online softmax; score rows live at row=(qd*4+r), col=nj*16+m16
        float alpha[2][4], psum[2][4];
#pragma unroll
        for (int mi = 0; mi < 2; ++mi)
#pragma unroll
            for (int r = 0; r < 4; ++r) {
                float mx = accS[mi][0][r];
#pragma unroll
                for (int nj = 1; nj < 8; ++nj) mx = fmaxf(mx, accS[mi][nj][r]);
#pragma unroll
                for (int off = 1; off < 16; off <<= 1) mx = fmaxf(mx, __shfl_xor(mx, off));
                float mn = fmaxf(mrow[mi][r], mx * scale);
                alpha[mi][r] = __expf(mrow[mi][r] - mn);
                mrow[mi][r] = mn;
                psum[mi][r] = 0.f;
            }
#pragma unroll
        for (int mi = 0; mi < 2; ++mi)
#pragma unroll
            for (int nj = 0; nj < 8; ++nj)
#pragma unroll
                for (int r = 0; r < 4; ++r) {
                    float p = __expf(accS[mi][nj][r] * scale - mrow[mi][r]);
                    psum[mi][r] += p;
                    KP[(wq + mi * 16 + qd * 4 + r) * 152 + nj * 16 + m16] = f32_to_bf16_rne(p);
                }
#pragma unroll
        for (int mi = 0; mi < 2; ++mi)
#pragma unroll
            for (int r = 0; r < 4; ++r) {
                float sum = psum[mi][r];
#pragma unroll
                for (int off = 1; off < 16; off <<= 1) sum += __shfl_xor(sum, off);
                lrow[mi][r] = lrow[mi][r] * alpha[mi][r] + sum;
            }
#pragma unroll
        for (int mi = 0; mi < 2; ++mi)
#pragma unroll
            for (int dj = 0; dj < 8; ++dj)
#pragma unroll
                for (int r = 0; r < 4; ++r) accO[mi][dj][r] *= alpha[mi][r];

        // PV: A-frag = P[s_q][s_k] (own wave's rows only — no barrier needed),
        //     B-frag = V[s_k = ks*32+qd*8+j][d = dj*16+m16] via VT[d][s_k]
#pragma unroll
        for (int ks = 0; ks < 4; ++ks) {
            s16x8 pf0 = *reinterpret_cast<const s16x8*>(&KP[(wq + m16) * 152 + ks * 32 + qd * 8]);
            s16x8 pf1 = *reinterpret_cast<const s16x8*>(&KP[(wq + 16 + m16) * 152 + ks * 32 + qd * 8]);
#pragma unroll
            for (int dj = 0; dj < 8; ++dj) {
                s16x8 vf = *reinterpret_cast<const s16x8*>(&VT[(dj * 16 + m16) * 152 + ks * 32 + qd * 8]);
                accO[0][dj] = __builtin_amdgcn_mfma_f32_16x16x32_bf16(pf0, vf, accO[0][dj], 0, 0, 0);
                accO[1][dj] = __builtin_amdgcn_mfma_f32_16x16x32_bf16(pf1, vf, accO[1][dj], 0, 0, 0);
            }
        }
    }
    // epilogue: out[b, s, h*128 + d] bf16
#pragma unroll
    for (int mi = 0; mi < 2; ++mi)
#pragma unroll
        for (int r = 0; r < 4; ++r) {
            float inv = 1.0f / lrow[mi][r];
            size_t row = (size_t)b * 2048 + q0 + wq + mi * 16 + qd * 4 + r;
#pragma unroll
            for (int dj = 0; dj < 8; ++dj)
                out[row * 2048 + h * 128 + dj * 16 + m16] =
                    f32_to_bf16_rne(accO[mi][dj][r] * inv);
        }
}

// ---------- launch ----------
extern "C" void kernel_launch(void* const* d_in, const int* in_sizes, int n_in,
                              void* d_out, int out_size, void* d_ws, size_t ws_size,
                              hipStream_t stream) {
    const float* x     = (const float*)d_in[0];   // 4096 x 2048
    const float* W_qkv = (const float*)d_in[1];   // 2048 x 6144
    const float* W_out = (const float*)d_in[2];   // 2048 x 2048
    float* out = (float*)d_out;                   // 4096 x 2048

    char* ws = (char*)d_ws;
    u16* xb   = (u16*)(ws);                          // 16 MiB  (4096x2048)
    u16* Wqt  = (u16*)(ws + (16u << 20));            // 24 MiB  (6144x2048)
    u16* Wot  = (u16*)(ws + (40u << 20));            //  8 MiB  (2048x2048)
    u16* qkvb = (u16*)(ws + (48u << 20));            // 48 MiB  (4096x6144)
    u16* attn = (u16*)(ws + (96u << 20));            // 16 MiB  (4096x2048)
    u16* vtg  = (u16*)(ws + (112u << 20));           // 16 MiB  (32x128x2048)

    k_cast<<<8192, 256, 0, stream>>>(x, xb);
    k_transpose_cast<<<dim3(96, 32), 256, 0, stream>>>(W_qkv, Wqt, 2048, 6144);
    k_transpose_cast<<<dim3(32, 32), 256, 0, stream>>>(W_out, Wot, 2048, 2048);
    k_gemm_bt<true><<<dim3(48, 32), 256, 0, stream>>>(xb, Wqt, qkvb, 4096, 6144, 2048);
    k_rope<<<32768, 256, 0, stream>>>(qkvb);
    k_transpose_v<<<dim3(32, 64), 256, 0, stream>>>(qkvb, vtg);
    k_flash<<<dim3(16, 32), 256, 0, stream>>>(qkvb, vtg, attn);
    k_gemm_bt<false><<<dim3(16, 32), 256, 0, stream>>>(attn, Wot, out, 4096, 2048, 2048);
}